// Round 6
// baseline (522.383 us; speedup 1.0000x reference)
//
#include <hip/hip_runtime.h>
#include <cstdint>
#include <cstddef>

#define DEVINL __device__ __forceinline__

typedef __bf16 bf16x8 __attribute__((ext_vector_type(8)));
typedef float  f32x4  __attribute__((ext_vector_type(4)));

// ---------------- helpers ----------------

DEVINL unsigned short f2b(float f) {   // f32 -> bf16 bits, round-to-nearest-even
  unsigned u = __builtin_bit_cast(unsigned, f);
  u += 0x7fffu + ((u >> 16) & 1u);
  return (unsigned short)(u >> 16);
}

DEVINL unsigned packtrunc(float a, float b) {  // 2x f32 -> packed bf16 (truncate)
  unsigned ua = __builtin_bit_cast(unsigned, a);
  unsigned ub = __builtin_bit_cast(unsigned, b);
  return (ua >> 16) | (ub & 0xffff0000u);
}

DEVINL void async16(void* lds, const void* g) {
  __builtin_amdgcn_global_load_lds((const __attribute__((address_space(1))) unsigned*)g,
                                   (__attribute__((address_space(3))) unsigned*)lds,
                                   16, 0, 0);
}

// ---------------- fused weight f32 -> bf16 cast (all 4 weights, 1 launch) ----------------
// mlp_w1 rows INTERLEAVED: gate row i -> 2i, up row i -> 2i+1 (GLU via shfl_xor(1)).

__global__ void cvt4_kernel(const float* __restrict__ s0, const float* __restrict__ s1,
                            const float* __restrict__ s2, const float* __restrict__ s3,
                            unsigned short* __restrict__ d0, unsigned short* __restrict__ d1,
                            unsigned short* __restrict__ d2, unsigned short* __restrict__ d3) {
  int i = blockIdx.x * 256 + threadIdx.x;   // float4 index, total 4194304
  if (i < 786432) {
    float4 v = ((const float4*)s0)[i];
    ushort4 o; o.x = f2b(v.x); o.y = f2b(v.y); o.z = f2b(v.z); o.w = f2b(v.w);
    ((ushort4*)d0)[i] = o;
  } else if (i < 1048576) {
    int off = i - 786432;
    float4 v = ((const float4*)s1)[off];
    ushort4 o; o.x = f2b(v.x); o.y = f2b(v.y); o.z = f2b(v.z); o.w = f2b(v.w);
    ((ushort4*)d1)[off] = o;
  } else if (i < 3145728) {
    int off = i - 1048576;                  // mlp_w1: 8192 rows x 256 float4
    int row = off >> 8, col = off & 255;
    int rp = (row < 4096) ? (row << 1) : (((row - 4096) << 1) | 1);
    float4 v = ((const float4*)s2)[off];
    ushort4 o; o.x = f2b(v.x); o.y = f2b(v.y); o.z = f2b(v.z); o.w = f2b(v.w);
    ((ushort4*)d2)[rp * 256 + col] = o;
  } else {
    int off = i - 3145728;
    float4 v = ((const float4*)s3)[off];
    ushort4 o; o.x = f2b(v.x); o.y = f2b(v.y); o.z = f2b(v.z); o.w = f2b(v.w);
    ((ushort4*)d3)[off] = o;
  }
}

// ---------------- conditioning: silu(c) @ {shift,scale}_w^T + b ----------------

__global__ void cond_kernel(const float* __restrict__ c,
                            const float* __restrict__ scale_w, const float* __restrict__ scale_b,
                            const float* __restrict__ shift_w, const float* __restrict__ shift_b,
                            float* __restrict__ scale_o, float* __restrict__ shift_o) {
  __shared__ float sc[1024];
  __shared__ float red[2][4][64];
  int tid = threadIdx.x;
  int b = blockIdx.x >> 4, ch = blockIdx.x & 15;
  for (int i = tid; i < 1024; i += 256) {
    float cv = c[b * 1024 + i];
    sc[i] = cv / (1.f + __expf(-cv));
  }
  __syncthreads();
  int colidx = tid & 63, p = tid >> 6;
  int co = ch * 64 + colidx;
  float dsc = 0.f, dsh = 0.f;
  for (int i = 0; i < 256; ++i) {
    int kk = p * 256 + i;
    float s = sc[kk];
    dsc += s * scale_w[(size_t)co * 1024 + kk];
    dsh += s * shift_w[(size_t)co * 1024 + kk];
  }
  red[0][p][colidx] = dsc;
  red[1][p][colidx] = dsh;
  __syncthreads();
  if (p == 0) {
    float s4  = red[0][0][colidx] + red[0][1][colidx] + red[0][2][colidx] + red[0][3][colidx];
    float sh4 = red[1][0][colidx] + red[1][1][colidx] + red[1][2][colidx] + red[1][3][colidx];
    scale_o[b * 1024 + co] = fminf(fmaxf(s4 + scale_b[co] + 1.f, 0.1f), 10.f);
    shift_o[b * 1024 + co] = sh4 + shift_b[co];
  }
}

// ---------------- adaLN ----------------

__global__ __launch_bounds__(256) void adaln_kernel(const float* __restrict__ x,
                                                    const float* __restrict__ norm_w,
                                                    const float* __restrict__ scale,
                                                    const float* __restrict__ shift,
                                                    unsigned short* __restrict__ h) {
  int row = blockIdx.x;
  int b = row >> 11;
  int tid = threadIdx.x;
  float4 v = ((const float4*)(x + (size_t)row * 1024))[tid];
  float ss = v.x * v.x + v.y * v.y + v.z * v.z + v.w * v.w;
  #pragma unroll
  for (int d = 32; d; d >>= 1) ss += __shfl_xor(ss, d);
  __shared__ float wsum[4];
  if ((tid & 63) == 0) wsum[tid >> 6] = ss;
  __syncthreads();
  float tot = wsum[0] + wsum[1] + wsum[2] + wsum[3];
  float inv = 1.f / fmaxf(sqrtf(tot * (1.f / 1024.f)), 1e-6f);
  float4 nw  = ((const float4*)norm_w)[tid];
  float4 scv = ((const float4*)(scale + b * 1024))[tid];
  float4 shv = ((const float4*)(shift + b * 1024))[tid];
  ushort4 o;
  o.x = f2b(v.x * inv * nw.x * scv.x + shv.x);
  o.y = f2b(v.y * inv * nw.y * scv.y + shv.y);
  o.z = f2b(v.z * inv * nw.z * scv.z + shv.z);
  o.w = f2b(v.w * inv * nw.w * scv.w + shv.w);
  ((ushort4*)(h + (size_t)row * 1024))[tid] = o;
}

// ---------------- MT x 128 bf16 MFMA GEMM:  C = A[M,K] @ B[N,K]^T ----------------

template<int EPI, int MT>
__global__ __launch_bounds__(256, 1) void gemm_k(
    const unsigned short* __restrict__ A,
    const unsigned short* __restrict__ B0,
    const float* __restrict__ bias0,
    const float* __restrict__ resid,
    void* __restrict__ out0_, void* __restrict__ out1_, void* __restrict__ out2_,
    int M, int N, int K) {
  constexpr int MI = MT / 32;              // m-frags per wave
  constexpr int A_SH = MT * 32;            // shorts per A half-buffer
  constexpr int COMPUTE_SH = 2 * A_SH + 2 * 4096;
  constexpr int STAGE_SH = (EPI == 1) ? 128 * 136 : (EPI == 2 ? 128 * 72 : 0);
  constexpr int SMEM_SH = (COMPUTE_SH > STAGE_SH) ? COMPUTE_SH : STAGE_SH;
  __shared__ __align__(16) unsigned short smem[SMEM_SH];
  unsigned short* As0 = smem;
  unsigned short* As1 = smem + A_SH;
  unsigned short* Bs0 = smem + 2 * A_SH;
  unsigned short* Bs1 = smem + 2 * A_SH + 4096;

  const int tid = threadIdx.x;
  const int wave = tid >> 6, lane = tid & 63;
  const int quad = lane >> 4, l16 = lane & 15;
  const int wm = (wave >> 1) * (MT / 2), wn = (wave & 1) * 64;
  const int bm = blockIdx.y * MT, bn = blockIdx.x * 128;

  f32x4 acc[MI][4] = {};

  const int steps = K >> 6;
  for (int s = 0; s < steps; ++s) {
    const int k0 = s << 6;
    __syncthreads();
    #pragma unroll
    for (int i = 0; i < MT / 64; ++i) {
      int cc = i * 256 + tid;
      int r = cc >> 2, ko = (cc & 3) << 3;
      size_t ga = (size_t)(bm + r) * K + k0 + ko;
      async16(As0 + (i * 2048 + wave * 512), A + ga);
      async16(As1 + (i * 2048 + wave * 512), A + ga + 32);
    }
    #pragma unroll
    for (int i = 0; i < 2; ++i) {
      int cc = i * 256 + tid;
      int r = cc >> 2, ko = (cc & 3) << 3;
      size_t gb = (size_t)(bn + r) * K + k0 + ko;
      async16(Bs0 + (i * 2048 + wave * 512), B0 + gb);
      async16(Bs1 + (i * 2048 + wave * 512), B0 + gb + 32);
    }
    __syncthreads();
    #pragma unroll
    for (int ks = 0; ks < 2; ++ks) {
      const unsigned short* Ah = ks ? As1 : As0;
      const unsigned short* Bh = ks ? Bs1 : Bs0;
      bf16x8 af[MI], bfr[4];
      #pragma unroll
      for (int mi = 0; mi < MI; ++mi)
        af[mi] = *reinterpret_cast<const bf16x8*>(&Ah[(wm + mi * 16 + l16) * 32 + quad * 8]);
      #pragma unroll
      for (int ni = 0; ni < 4; ++ni)
        bfr[ni] = *reinterpret_cast<const bf16x8*>(&Bh[(wn + ni * 16 + l16) * 32 + quad * 8]);
      #pragma unroll
      for (int mi = 0; mi < MI; ++mi)
        #pragma unroll
        for (int ni = 0; ni < 4; ++ni)
          acc[mi][ni] = __builtin_amdgcn_mfma_f32_16x16x32_bf16(af[mi], bfr[ni], acc[mi][ni], 0, 0, 0);
    }
  }

  // ---------- epilogue: C/D layout col=lane&15, row=quad*4+reg ----------
  if constexpr (EPI == 0) {
    #pragma unroll
    for (int mi = 0; mi < MI; ++mi) {
      #pragma unroll
      for (int ni = 0; ni < 4; ++ni) {
        int gc = bn + wn + ni * 16 + l16;
        #pragma unroll
        for (int r = 0; r < 4; ++r) {
          int gr = bm + wm + mi * 16 + quad * 4 + r;
          ((float*)out0_)[(size_t)gr * N + gc] = acc[mi][ni][r] + bias0[gc] + resid[(size_t)gr * N + gc];
        }
      }
    }
  } else if constexpr (EPI == 1) {
    const int region = bn >> 10;          // 0=q, 1=k, 2=v
    __syncthreads();
    #pragma unroll
    for (int mi = 0; mi < MI; ++mi) {
      #pragma unroll
      for (int ni = 0; ni < 4; ++ni) {
        int lc = wn + ni * 16 + l16;
        #pragma unroll
        for (int r = 0; r < 4; ++r) {
          int lr = wm + mi * 16 + quad * 4 + r;
          float v = acc[mi][ni][r];
          if (region == 0)      smem[lr * 136 + lc] = f2b(v * 0.125f);
          else if (region == 1) smem[lr * 136 + lc] = f2b(v);
          else                  smem[lc * 136 + lr] = f2b(v);   // transpose for v
        }
      }
    }
    __syncthreads();
    const int b = bm >> 11;
    const int bnm = bn & 1023;
    if (region <= 1) {
      int lr = tid >> 1, hl = tid & 1;
      int n = (bm + lr) & 2047;
      int hh = (bnm >> 6) + hl;
      unsigned short* dst = (unsigned short*)(region == 0 ? out0_ : out1_) +
                            (((size_t)(b * 16 + hh)) * 2048 + n) * 64;
      const unsigned short* src = smem + lr * 136 + hl * 64;
      #pragma unroll
      for (int j = 0; j < 8; ++j)
        ((uint4*)dst)[j] = *(const uint4*)(src + j * 8);
    } else {
      int lc = tid >> 1, nh = tid & 1;
      int c2 = bnm + lc;
      int hh = c2 >> 6, d = c2 & 63;
      int nbase = (bm & 2047) + nh * 64;
      unsigned short* dst = (unsigned short*)out2_ +
                            (((size_t)(b * 16 + hh)) * 64 + d) * 2048 + nbase;
      const unsigned short* src = smem + lc * 136 + nh * 64;
      #pragma unroll
      for (int j = 0; j < 8; ++j)
        ((uint4*)dst)[j] = *(const uint4*)(src + j * 8);
    }
  } else {   // EPI 2: interleaved GLU -> bf16 [M, N/2]
    __syncthreads();
    #pragma unroll
    for (int mi = 0; mi < MI; ++mi) {
      #pragma unroll
      for (int ni = 0; ni < 4; ++ni) {
        int lc = wn + ni * 16 + l16;
        int gcp = bn + lc;
        int gi = gcp >> 1;
        float bias = bias0[(gcp & 1) ? 4096 + gi : gi];
        #pragma unroll
        for (int r = 0; r < 4; ++r) {
          int lr = wm + mi * 16 + quad * 4 + r;
          float v = acc[mi][ni][r] + bias;
          float p = __shfl_xor(v, 1);
          if ((l16 & 1) == 0) {
            float g = (v / (1.f + __expf(-v))) * p;
            smem[lr * 72 + (lc >> 1)] = f2b(g);
          }
        }
      }
    }
    __syncthreads();
    int lr = tid >> 1, ch = (tid & 1) * 32;
    unsigned short* dst = (unsigned short*)out0_ + (size_t)(bm + lr) * (N >> 1) + (bn >> 1) + ch;
    const unsigned short* src = smem + lr * 72 + ch;
    #pragma unroll
    for (int j = 0; j < 4; ++j)
      ((uint4*)dst)[j] = *(const uint4*)(src + j * 8);
  }
}

// ---------------- flash attention (S^T formulation, Q-tile 128, K-tile 128) ----------------
// Per wave: 32 q-rows (2 m-frags). 64 MFMA per barrier-pair; softmax rescale
// once per 128 keys. LDS: Ks 16K + Vs 16K + Ps 34K = ~67KB -> 2 blocks/CU.

__global__ __launch_bounds__(256, 1) void attn_kernel(
    const unsigned short* __restrict__ q, const unsigned short* __restrict__ k,
    const unsigned short* __restrict__ vt, const int* __restrict__ amask,
    unsigned short* __restrict__ o) {
  const int bh = blockIdx.x;
  const int b = bh >> 4, h = bh & 15;
  const int qt = blockIdx.y;
  const int tid = threadIdx.x;
  const int wave = tid >> 6, lane = tid & 63;
  const int quad = lane >> 4, l16 = lane & 15;
  const int h7 = l16 & 7;
  const int kc0 = (quad ^ h7) * 8;          // K frag chunks (8x16B rows)
  const int kc1 = ((quad + 4) ^ h7) * 8;

  const unsigned short* qb = q  + (size_t)bh * 2048 * 64;
  const unsigned short* kb = k  + (size_t)bh * 2048 * 64;
  const unsigned short* vb = vt + (size_t)bh * 64 * 2048;

  __shared__ __align__(16) unsigned short Ks[128 * 64];    // [key][d], chunk-swizzled (8/row)
  __shared__ __align__(16) unsigned short Vs[64 * 128];    // [d][key], chunk-swizzled (16/row)
  __shared__ __align__(16) unsigned short Ps[4 * 2 * 16 * 136];  // P stage / epilogue stage
  __shared__ float biasf[128];

  unsigned short* Psm[2] = { Ps + wave * 4352, Ps + wave * 4352 + 2176 };

  bf16x8 qa[2][2];
  #pragma unroll
  for (int m = 0; m < 2; ++m) {
    int qrow = qt * 128 + wave * 32 + m * 16 + l16;
    qa[m][0] = *reinterpret_cast<const bf16x8*>(&qb[(size_t)qrow * 64 + quad * 8]);
    qa[m][1] = *reinterpret_cast<const bf16x8*>(&qb[(size_t)qrow * 64 + 32 + quad * 8]);
  }

  f32x4 oacc[2][4] = {};
  float mrow[2] = {-30000.f, -30000.f}, lrow[2] = {0.f, 0.f};

  // prefetch tile 0 (store-slot cc -> swizzled global source)
  uint4 kpre[4], vpre[4];
  #pragma unroll
  for (int i = 0; i < 4; ++i) {
    int cc = i * 256 + tid;
    int key = cc >> 3, dl = (cc & 7) ^ (key & 7);
    kpre[i] = *(const uint4*)(kb + key * 64 + dl * 8);
    int d = cc >> 4, kl = (cc & 15) ^ (d & 15);
    vpre[i] = *(const uint4*)(vb + (size_t)d * 2048 + kl * 8);
  }
  int mv = (tid < 128) ? amask[b * 2048 + tid] : 0;

  for (int kt = 0; kt < 16; ++kt) {
    __syncthreads();
    #pragma unroll
    for (int i = 0; i < 4; ++i) {
      ((uint4*)Ks)[i * 256 + tid] = kpre[i];
      ((uint4*)Vs)[i * 256 + tid] = vpre[i];
    }
    if (tid < 128) biasf[tid] = mv ? 0.f : -30000.f;
    __syncthreads();

    if (kt + 1 < 16) {   // prefetch next tile during compute
      #pragma unroll
      for (int i = 0; i < 4; ++i) {
        int cc = i * 256 + tid;
        int key = cc >> 3, dl = (cc & 7) ^ (key & 7);
        kpre[i] = *(const uint4*)(kb + (size_t)(kt + 1) * 8192 + key * 64 + dl * 8);
        int d = cc >> 4, kl = (cc & 15) ^ (d & 15);
        vpre[i] = *(const uint4*)(vb + (size_t)d * 2048 + (kt + 1) * 128 + kl * 8);
      }
      mv = (tid < 128) ? amask[b * 2048 + (kt + 1) * 128 + tid] : 0;
    }

    // S^T: lane holds S[q=l16][key=nt*16+quad*4+r], nt 0..7
    f32x4 st[2][8];
    #pragma unroll
    for (int nt = 0; nt < 8; ++nt) {
      bf16x8 ka0 = *reinterpret_cast<const bf16x8*>(&Ks[(nt * 16 + l16) * 64 + kc0]);
      bf16x8 ka1 = *reinterpret_cast<const bf16x8*>(&Ks[(nt * 16 + l16) * 64 + kc1]);
      f32x4 bv = *reinterpret_cast<const f32x4*>(&biasf[nt * 16 + quad * 4]);
      #pragma unroll
      for (int m = 0; m < 2; ++m) {
        f32x4 z = {};
        z = __builtin_amdgcn_mfma_f32_16x16x32_bf16(ka0, qa[m][0], z, 0, 0, 0);
        z = __builtin_amdgcn_mfma_f32_16x16x32_bf16(ka1, qa[m][1], z, 0, 0, 0);
        st[m][nt] = z + bv;
      }
    }

    #pragma unroll
    for (int m = 0; m < 2; ++m) {
      float tm = -1e30f;
      #pragma unroll
      for (int nt = 0; nt < 8; ++nt)
        #pragma unroll
        for (int r = 0; r < 4; ++r) tm = fmaxf(tm, st[m][nt][r]);
      tm = fmaxf(tm, __shfl_xor(tm, 16));
      tm = fmaxf(tm, __shfl_xor(tm, 32));

      float mnew = fmaxf(mrow[m], tm);
      float alpha = __expf(mrow[m] - mnew);
      mrow[m] = mnew;

      float rs = 0.f;
      #pragma unroll
      for (int nt = 0; nt < 8; ++nt) {
        float p0 = __expf(st[m][nt][0] - mnew);
        float p1 = __expf(st[m][nt][1] - mnew);
        float p2 = __expf(st[m][nt][2] - mnew);
        float p3 = __expf(st[m][nt][3] - mnew);
        rs += (p0 + p1) + (p2 + p3);
        uint2 w;
        w.x = packtrunc(p0, p1);
        w.y = packtrunc(p2, p3);
        *(uint2*)&Psm[m][l16 * 136 + nt * 16 + quad * 4] = w;
      }
      rs += __shfl_xor(rs, 16);
      rs += __shfl_xor(rs, 32);
      lrow[m] = lrow[m] * alpha + rs;

      float a0 = __shfl(alpha, quad * 4 + 0);
      float a1 = __shfl(alpha, quad * 4 + 1);
      float a2 = __shfl(alpha, quad * 4 + 2);
      float a3 = __shfl(alpha, quad * 4 + 3);
      #pragma unroll
      for (int dt = 0; dt < 4; ++dt) {
        oacc[m][dt][0] *= a0; oacc[m][dt][1] *= a1;
        oacc[m][dt][2] *= a2; oacc[m][dt][3] *= a3;
      }
    }

    // PV: A = P rows (per-wave LDS), B = V^T rows; 4 key-chunks of 32
    #pragma unroll
    for (int ks = 0; ks < 4; ++ks) {
      bf16x8 pa[2];
      #pragma unroll
      for (int m = 0; m < 2; ++m)
        pa[m] = *reinterpret_cast<const bf16x8*>(&Psm[m][l16 * 136 + ks * 32 + quad * 8]);
      #pragma unroll
      for (int dt = 0; dt < 4; ++dt) {
        bf16x8 vbf = *reinterpret_cast<const bf16x8*>(
            &Vs[(dt * 16 + l16) * 128 + (((ks * 4 + quad) ^ l16) * 8)]);
        #pragma unroll
        for (int m = 0; m < 2; ++m)
          oacc[m][dt] = __builtin_amdgcn_mfma_f32_16x16x32_bf16(pa[m], vbf, oacc[m][dt], 0, 0, 0);
      }
    }
  }

  float iv[2][4];
  #pragma unroll
  for (int m = 0; m < 2; ++m) {
    float invl = lrow[m] > 0.f ? 1.f / lrow[m] : 0.f;
    #pragma unroll
    for (int r = 0; r < 4; ++r) iv[m][r] = __shfl(invl, quad * 4 + r);
  }
  __syncthreads();
  #pragma unroll
  for (int m = 0; m < 2; ++m)
    #pragma unroll
    for (int dt = 0; dt < 4; ++dt)
      #pragma unroll
      for (int r = 0; r < 4; ++r) {
        int lr = wave * 32 + m * 16 + quad * 4 + r;
        Ps[lr * 72 + dt * 16 + l16] = f2b(oacc[m][dt][r] * iv[m][r]);
      }
  __syncthreads();
  {
    int lr = tid >> 1, cb = (tid & 1) * 32;
    int n = qt * 128 + lr;
    unsigned short* dst = o + ((size_t)(b * 2048 + n)) * 1024 + h * 64 + cb;
    const unsigned short* src = Ps + lr * 72 + cb;
    #pragma unroll
    for (int j = 0; j < 4; ++j)
      ((uint4*)dst)[j] = *(const uint4*)(src + j * 8);
  }
}

// ---------------- launch ----------------

extern "C" void kernel_launch(void* const* d_in, const int* in_sizes, int n_in,
                              void* d_out, int out_size, void* d_ws, size_t ws_size,
                              hipStream_t stream) {
  const float* x       = (const float*)d_in[0];
  const float* c       = (const float*)d_in[1];
  const int*   amask   = (const int*)d_in[2];
  const float* norm_w  = (const float*)d_in[3];
  const float* scale_w = (const float*)d_in[4];
  const float* scale_b = (const float*)d_in[5];
  const float* shift_w = (const float*)d_in[6];
  const float* shift_b = (const float*)d_in[7];
  const float* qkv_w   = (const float*)d_in[8];
  const float* proj_w  = (const float*)d_in[9];
  const float* proj_b  = (const float*)d_in[10];
  const float* mlp_w1  = (const float*)d_in[11];
  const float* mlp_b1  = (const float*)d_in[12];
  const float* mlp_w2  = (const float*)d_in[13];
  const float* mlp_b2  = (const float*)d_in[14];

  char* ws = (char*)d_ws;
  unsigned short* wqkv  = (unsigned short*)(ws + 0);
  unsigned short* wproj = (unsigned short*)(ws + 6291456);
  unsigned short* wmlp1 = (unsigned short*)(ws + 8388608);   // interleaved gate/up rows
  unsigned short* wmlp2 = (unsigned short*)(ws + 25165824);
  float* scale_o        = (float*)(ws + 33554432);
  float* shift_o        = (float*)(ws + 33562624);
  unsigned short* hbuf  = (unsigned short*)(ws + 33570816);
  unsigned short* qbuf  = (unsigned short*)(ws + 41959424);
  unsigned short* kbuf  = (unsigned short*)(ws + 50348032);
  unsigned short* vbuf  = (unsigned short*)(ws + 58736640);
  unsigned short* abuf  = (unsigned short*)(ws + 67125248);
  unsigned short* gbuf  = qbuf;
  float* x1             = (float*)(ws + 75513856);

  cvt4_kernel<<<16384, 256, 0, stream>>>(qkv_w, proj_w, mlp_w1, mlp_w2,
                                         wqkv, wproj, wmlp1, wmlp2);

  cond_kernel<<<32, 256, 0, stream>>>(c, scale_w, scale_b, shift_w, shift_b, scale_o, shift_o);

  adaln_kernel<<<4096, 256, 0, stream>>>(x, norm_w, scale_o, shift_o, hbuf);

  gemm_k<1, 128><<<dim3(24, 32), 256, 0, stream>>>(hbuf, wqkv, nullptr, nullptr,
                                                   qbuf, kbuf, vbuf, 4096, 3072, 1024);

  attn_kernel<<<dim3(32, 16), 256, 0, stream>>>(qbuf, kbuf, vbuf, amask, abuf);

  gemm_k<0, 64><<<dim3(8, 64), 256, 0, stream>>>(abuf, wproj, proj_b, x,
                                                 x1, nullptr, nullptr, 4096, 1024, 1024);

  adaln_kernel<<<4096, 256, 0, stream>>>(x1, norm_w, scale_o, shift_o, hbuf);

  gemm_k<2, 128><<<dim3(64, 32), 256, 0, stream>>>(hbuf, wmlp1, mlp_b1, nullptr,
                                                   gbuf, nullptr, nullptr, 4096, 8192, 1024);

  gemm_k<0, 64><<<dim3(8, 64), 256, 0, stream>>>(gbuf, wmlp2, mlp_b2, x1,
                                                 d_out, nullptr, nullptr, 4096, 1024, 4096);

  (void)in_sizes; (void)n_in; (void)out_size; (void)ws_size;
}

// Round 7
// 479.528 us; speedup vs baseline: 1.0894x; 1.0894x over previous
//
#include <hip/hip_runtime.h>
#include <cstdint>
#include <cstddef>

#define DEVINL __device__ __forceinline__

typedef __bf16 bf16x8 __attribute__((ext_vector_type(8)));
typedef float  f32x4  __attribute__((ext_vector_type(4)));

// ---------------- helpers ----------------

DEVINL unsigned short f2b(float f) {   // f32 -> bf16 bits, round-to-nearest-even
  unsigned u = __builtin_bit_cast(unsigned, f);
  u += 0x7fffu + ((u >> 16) & 1u);
  return (unsigned short)(u >> 16);
}

DEVINL unsigned packtrunc(float a, float b) {  // 2x f32 -> packed bf16 (truncate)
  unsigned ua = __builtin_bit_cast(unsigned, a);
  unsigned ub = __builtin_bit_cast(unsigned, b);
  return (ua >> 16) | (ub & 0xffff0000u);
}

DEVINL void async16(void* lds, const void* g) {
  __builtin_amdgcn_global_load_lds((const __attribute__((address_space(1))) unsigned*)g,
                                   (__attribute__((address_space(3))) unsigned*)lds,
                                   16, 0, 0);
}

// ---------------- fused weight f32 -> bf16 cast (all 4 weights, 1 launch) ----------------
// mlp_w1 rows INTERLEAVED: gate row i -> 2i, up row i -> 2i+1 (GLU via shfl_xor(1)).

__global__ void cvt4_kernel(const float* __restrict__ s0, const float* __restrict__ s1,
                            const float* __restrict__ s2, const float* __restrict__ s3,
                            unsigned short* __restrict__ d0, unsigned short* __restrict__ d1,
                            unsigned short* __restrict__ d2, unsigned short* __restrict__ d3) {
  int i = blockIdx.x * 256 + threadIdx.x;   // float4 index, total 4194304
  if (i < 786432) {
    float4 v = ((const float4*)s0)[i];
    ushort4 o; o.x = f2b(v.x); o.y = f2b(v.y); o.z = f2b(v.z); o.w = f2b(v.w);
    ((ushort4*)d0)[i] = o;
  } else if (i < 1048576) {
    int off = i - 786432;
    float4 v = ((const float4*)s1)[off];
    ushort4 o; o.x = f2b(v.x); o.y = f2b(v.y); o.z = f2b(v.z); o.w = f2b(v.w);
    ((ushort4*)d1)[off] = o;
  } else if (i < 3145728) {
    int off = i - 1048576;                  // mlp_w1: 8192 rows x 256 float4
    int row = off >> 8, col = off & 255;
    int rp = (row < 4096) ? (row << 1) : (((row - 4096) << 1) | 1);
    float4 v = ((const float4*)s2)[off];
    ushort4 o; o.x = f2b(v.x); o.y = f2b(v.y); o.z = f2b(v.z); o.w = f2b(v.w);
    ((ushort4*)d2)[rp * 256 + col] = o;
  } else {
    int off = i - 3145728;
    float4 v = ((const float4*)s3)[off];
    ushort4 o; o.x = f2b(v.x); o.y = f2b(v.y); o.z = f2b(v.z); o.w = f2b(v.w);
    ((ushort4*)d3)[off] = o;
  }
}

// ---------------- conditioning: silu(c) @ {shift,scale}_w^T + b ----------------

__global__ void cond_kernel(const float* __restrict__ c,
                            const float* __restrict__ scale_w, const float* __restrict__ scale_b,
                            const float* __restrict__ shift_w, const float* __restrict__ shift_b,
                            float* __restrict__ scale_o, float* __restrict__ shift_o) {
  __shared__ float sc[1024];
  __shared__ float red[2][4][64];
  int tid = threadIdx.x;
  int b = blockIdx.x >> 4, ch = blockIdx.x & 15;
  for (int i = tid; i < 1024; i += 256) {
    float cv = c[b * 1024 + i];
    sc[i] = cv / (1.f + __expf(-cv));
  }
  __syncthreads();
  int colidx = tid & 63, p = tid >> 6;
  int co = ch * 64 + colidx;
  float dsc = 0.f, dsh = 0.f;
  for (int i = 0; i < 256; ++i) {
    int kk = p * 256 + i;
    float s = sc[kk];
    dsc += s * scale_w[(size_t)co * 1024 + kk];
    dsh += s * shift_w[(size_t)co * 1024 + kk];
  }
  red[0][p][colidx] = dsc;
  red[1][p][colidx] = dsh;
  __syncthreads();
  if (p == 0) {
    float s4  = red[0][0][colidx] + red[0][1][colidx] + red[0][2][colidx] + red[0][3][colidx];
    float sh4 = red[1][0][colidx] + red[1][1][colidx] + red[1][2][colidx] + red[1][3][colidx];
    scale_o[b * 1024 + co] = fminf(fmaxf(s4 + scale_b[co] + 1.f, 0.1f), 10.f);
    shift_o[b * 1024 + co] = sh4 + shift_b[co];
  }
}

// ---------------- adaLN ----------------

__global__ __launch_bounds__(256) void adaln_kernel(const float* __restrict__ x,
                                                    const float* __restrict__ norm_w,
                                                    const float* __restrict__ scale,
                                                    const float* __restrict__ shift,
                                                    unsigned short* __restrict__ h) {
  int row = blockIdx.x;
  int b = row >> 11;
  int tid = threadIdx.x;
  float4 v = ((const float4*)(x + (size_t)row * 1024))[tid];
  float ss = v.x * v.x + v.y * v.y + v.z * v.z + v.w * v.w;
  #pragma unroll
  for (int d = 32; d; d >>= 1) ss += __shfl_xor(ss, d);
  __shared__ float wsum[4];
  if ((tid & 63) == 0) wsum[tid >> 6] = ss;
  __syncthreads();
  float tot = wsum[0] + wsum[1] + wsum[2] + wsum[3];
  float inv = 1.f / fmaxf(sqrtf(tot * (1.f / 1024.f)), 1e-6f);
  float4 nw  = ((const float4*)norm_w)[tid];
  float4 scv = ((const float4*)(scale + b * 1024))[tid];
  float4 shv = ((const float4*)(shift + b * 1024))[tid];
  ushort4 o;
  o.x = f2b(v.x * inv * nw.x * scv.x + shv.x);
  o.y = f2b(v.y * inv * nw.y * scv.y + shv.y);
  o.z = f2b(v.z * inv * nw.z * scv.z + shv.z);
  o.w = f2b(v.w * inv * nw.w * scv.w + shv.w);
  ((ushort4*)(h + (size_t)row * 1024))[tid] = o;
}

// ---------------- MT x 128 bf16 MFMA GEMM:  C = A[M,K] @ B[N,K]^T ----------------

template<int EPI, int MT>
__global__ __launch_bounds__(256, 1) void gemm_k(
    const unsigned short* __restrict__ A,
    const unsigned short* __restrict__ B0,
    const float* __restrict__ bias0,
    const float* __restrict__ resid,
    void* __restrict__ out0_, void* __restrict__ out1_, void* __restrict__ out2_,
    int M, int N, int K) {
  constexpr int MI = MT / 32;              // m-frags per wave
  constexpr int A_SH = MT * 32;            // shorts per A half-buffer
  constexpr int COMPUTE_SH = 2 * A_SH + 2 * 4096;
  constexpr int STAGE_SH = (EPI == 1) ? 128 * 136 : (EPI == 2 ? 128 * 72 : 0);
  constexpr int SMEM_SH = (COMPUTE_SH > STAGE_SH) ? COMPUTE_SH : STAGE_SH;
  __shared__ __align__(16) unsigned short smem[SMEM_SH];
  unsigned short* As0 = smem;
  unsigned short* As1 = smem + A_SH;
  unsigned short* Bs0 = smem + 2 * A_SH;
  unsigned short* Bs1 = smem + 2 * A_SH + 4096;

  const int tid = threadIdx.x;
  const int wave = tid >> 6, lane = tid & 63;
  const int quad = lane >> 4, l16 = lane & 15;
  const int wm = (wave >> 1) * (MT / 2), wn = (wave & 1) * 64;
  const int bm = blockIdx.y * MT, bn = blockIdx.x * 128;

  f32x4 acc[MI][4] = {};

  const int steps = K >> 6;
  for (int s = 0; s < steps; ++s) {
    const int k0 = s << 6;
    __syncthreads();
    #pragma unroll
    for (int i = 0; i < MT / 64; ++i) {
      int cc = i * 256 + tid;
      int r = cc >> 2, ko = (cc & 3) << 3;
      size_t ga = (size_t)(bm + r) * K + k0 + ko;
      async16(As0 + (i * 2048 + wave * 512), A + ga);
      async16(As1 + (i * 2048 + wave * 512), A + ga + 32);
    }
    #pragma unroll
    for (int i = 0; i < 2; ++i) {
      int cc = i * 256 + tid;
      int r = cc >> 2, ko = (cc & 3) << 3;
      size_t gb = (size_t)(bn + r) * K + k0 + ko;
      async16(Bs0 + (i * 2048 + wave * 512), B0 + gb);
      async16(Bs1 + (i * 2048 + wave * 512), B0 + gb + 32);
    }
    __syncthreads();
    #pragma unroll
    for (int ks = 0; ks < 2; ++ks) {
      const unsigned short* Ah = ks ? As1 : As0;
      const unsigned short* Bh = ks ? Bs1 : Bs0;
      bf16x8 af[MI], bfr[4];
      #pragma unroll
      for (int mi = 0; mi < MI; ++mi)
        af[mi] = *reinterpret_cast<const bf16x8*>(&Ah[(wm + mi * 16 + l16) * 32 + quad * 8]);
      #pragma unroll
      for (int ni = 0; ni < 4; ++ni)
        bfr[ni] = *reinterpret_cast<const bf16x8*>(&Bh[(wn + ni * 16 + l16) * 32 + quad * 8]);
      #pragma unroll
      for (int mi = 0; mi < MI; ++mi)
        #pragma unroll
        for (int ni = 0; ni < 4; ++ni)
          acc[mi][ni] = __builtin_amdgcn_mfma_f32_16x16x32_bf16(af[mi], bfr[ni], acc[mi][ni], 0, 0, 0);
    }
  }

  // ---------- epilogue: C/D layout col=lane&15, row=quad*4+reg ----------
  if constexpr (EPI == 0) {
    #pragma unroll
    for (int mi = 0; mi < MI; ++mi) {
      #pragma unroll
      for (int ni = 0; ni < 4; ++ni) {
        int gc = bn + wn + ni * 16 + l16;
        #pragma unroll
        for (int r = 0; r < 4; ++r) {
          int gr = bm + wm + mi * 16 + quad * 4 + r;
          ((float*)out0_)[(size_t)gr * N + gc] = acc[mi][ni][r] + bias0[gc] + resid[(size_t)gr * N + gc];
        }
      }
    }
  } else if constexpr (EPI == 1) {
    const int region = bn >> 10;          // 0=q, 1=k, 2=v
    __syncthreads();
    #pragma unroll
    for (int mi = 0; mi < MI; ++mi) {
      #pragma unroll
      for (int ni = 0; ni < 4; ++ni) {
        int lc = wn + ni * 16 + l16;
        #pragma unroll
        for (int r = 0; r < 4; ++r) {
          int lr = wm + mi * 16 + quad * 4 + r;
          float v = acc[mi][ni][r];
          if (region == 0)      smem[lr * 136 + lc] = f2b(v * 0.125f);
          else if (region == 1) smem[lr * 136 + lc] = f2b(v);
          else                  smem[lc * 136 + lr] = f2b(v);   // transpose for v
        }
      }
    }
    __syncthreads();
    const int b = bm >> 11;
    const int bnm = bn & 1023;
    if (region <= 1) {
      int lr = tid >> 1, hl = tid & 1;
      int n = (bm + lr) & 2047;
      int hh = (bnm >> 6) + hl;
      unsigned short* dst = (unsigned short*)(region == 0 ? out0_ : out1_) +
                            (((size_t)(b * 16 + hh)) * 2048 + n) * 64;
      const unsigned short* src = smem + lr * 136 + hl * 64;
      #pragma unroll
      for (int j = 0; j < 8; ++j)
        ((uint4*)dst)[j] = *(const uint4*)(src + j * 8);
    } else {
      int lc = tid >> 1, nh = tid & 1;
      int c2 = bnm + lc;
      int hh = c2 >> 6, d = c2 & 63;
      int nbase = (bm & 2047) + nh * 64;
      unsigned short* dst = (unsigned short*)out2_ +
                            (((size_t)(b * 16 + hh)) * 64 + d) * 2048 + nbase;
      const unsigned short* src = smem + lc * 136 + nh * 64;
      #pragma unroll
      for (int j = 0; j < 8; ++j)
        ((uint4*)dst)[j] = *(const uint4*)(src + j * 8);
    }
  } else {   // EPI 2: interleaved GLU -> bf16 [M, N/2]
    __syncthreads();
    #pragma unroll
    for (int mi = 0; mi < MI; ++mi) {
      #pragma unroll
      for (int ni = 0; ni < 4; ++ni) {
        int lc = wn + ni * 16 + l16;
        int gcp = bn + lc;
        int gi = gcp >> 1;
        float bias = bias0[(gcp & 1) ? 4096 + gi : gi];
        #pragma unroll
        for (int r = 0; r < 4; ++r) {
          int lr = wm + mi * 16 + quad * 4 + r;
          float v = acc[mi][ni][r] + bias;
          float p = __shfl_xor(v, 1);
          if ((l16 & 1) == 0) {
            float g = (v / (1.f + __expf(-v))) * p;
            smem[lr * 72 + (lc >> 1)] = f2b(g);
          }
        }
      }
    }
    __syncthreads();
    int lr = tid >> 1, ch = (tid & 1) * 32;
    unsigned short* dst = (unsigned short*)out0_ + (size_t)(bm + lr) * (N >> 1) + (bn >> 1) + ch;
    const unsigned short* src = smem + lr * 72 + ch;
    #pragma unroll
    for (int j = 0; j < 4; ++j)
      ((uint4*)dst)[j] = *(const uint4*)(src + j * 8);
  }
}

// ---------------- flash attention (S^T, Q-tile 128, K-tile 64, 8 waves) ----------------
// block = 512 threads = 8 waves x 16 q-rows -> 16 waves/CU at grid 512 (2 blk/CU).
// Low register pressure (single m-frag, st[4], 2-uint4 prefetch) -> no spill.

__global__ __launch_bounds__(512, 1) void attn_kernel(
    const unsigned short* __restrict__ q, const unsigned short* __restrict__ k,
    const unsigned short* __restrict__ vt, const int* __restrict__ amask,
    unsigned short* __restrict__ o) {
  const int bh = blockIdx.x;
  const int b = bh >> 4, h = bh & 15;
  const int qt = blockIdx.y;
  const int tid = threadIdx.x;
  const int wave = tid >> 6, lane = tid & 63;
  const int quad = lane >> 4, l16 = lane & 15;
  const int h7 = l16 & 7;
  const int kc0 = (quad ^ h7) * 8;
  const int kc1 = ((quad + 4) ^ h7) * 8;

  const unsigned short* qb = q  + (size_t)bh * 2048 * 64;
  const unsigned short* kb = k  + (size_t)bh * 2048 * 64;
  const unsigned short* vb = vt + (size_t)bh * 64 * 2048;

  __shared__ __align__(16) unsigned short Ks[64 * 64];   // 8 KB, chunk-swizzled
  __shared__ __align__(16) unsigned short Vs[64 * 64];   // 8 KB, chunk-swizzled
  __shared__ __align__(16) unsigned short Ps[8 * 16 * 72];  // per-wave P / epilogue stage (18 KB)
  __shared__ float biasf[64];

  unsigned short* PsW = Ps + wave * 1152;

  const int qrow = qt * 128 + wave * 16 + l16;
  bf16x8 qa0 = *reinterpret_cast<const bf16x8*>(&qb[(size_t)qrow * 64 + quad * 8]);
  bf16x8 qa1 = *reinterpret_cast<const bf16x8*>(&qb[(size_t)qrow * 64 + 32 + quad * 8]);

  f32x4 oacc[4] = {};
  float mrow = -30000.f, lrow = 0.f;

  // prefetch tile 0: 512 threads x 16B = one 8KB tile each for K and V
  uint4 kpre, vpre;
  {
    int key = tid >> 3, dl = (tid & 7) ^ (key & 7);
    kpre = *(const uint4*)(kb + key * 64 + dl * 8);
    int d = tid >> 3, kl = (tid & 7) ^ (d & 7);
    vpre = *(const uint4*)(vb + (size_t)d * 2048 + kl * 8);
  }
  int mv = (tid < 64) ? amask[b * 2048 + tid] : 0;

  for (int kt = 0; kt < 32; ++kt) {
    __syncthreads();
    ((uint4*)Ks)[tid] = kpre;
    ((uint4*)Vs)[tid] = vpre;
    if (tid < 64) biasf[tid] = mv ? 0.f : -30000.f;
    __syncthreads();

    if (kt + 1 < 32) {   // prefetch next tile during compute
      int key = tid >> 3, dl = (tid & 7) ^ (key & 7);
      kpre = *(const uint4*)(kb + (size_t)(kt + 1) * 4096 + key * 64 + dl * 8);
      int d = tid >> 3, kl = (tid & 7) ^ (d & 7);
      vpre = *(const uint4*)(vb + (size_t)d * 2048 + (kt + 1) * 64 + kl * 8);
      mv = (tid < 64) ? amask[b * 2048 + (kt + 1) * 64 + tid] : 0;
    }

    // S^T: lane holds S[q=l16][key=nt*16+quad*4+r]
    f32x4 st[4];
    #pragma unroll
    for (int nt = 0; nt < 4; ++nt) {
      bf16x8 ka0 = *reinterpret_cast<const bf16x8*>(&Ks[(nt * 16 + l16) * 64 + kc0]);
      bf16x8 ka1 = *reinterpret_cast<const bf16x8*>(&Ks[(nt * 16 + l16) * 64 + kc1]);
      f32x4 bv = *reinterpret_cast<const f32x4*>(&biasf[nt * 16 + quad * 4]);
      f32x4 z = {};
      z = __builtin_amdgcn_mfma_f32_16x16x32_bf16(ka0, qa0, z, 0, 0, 0);
      z = __builtin_amdgcn_mfma_f32_16x16x32_bf16(ka1, qa1, z, 0, 0, 0);
      st[nt] = z + bv;
    }

    float tm = -1e30f;
    #pragma unroll
    for (int nt = 0; nt < 4; ++nt)
      #pragma unroll
      for (int r = 0; r < 4; ++r) tm = fmaxf(tm, st[nt][r]);
    tm = fmaxf(tm, __shfl_xor(tm, 16));
    tm = fmaxf(tm, __shfl_xor(tm, 32));

    float mnew = fmaxf(mrow, tm);
    float alpha = __expf(mrow - mnew);
    mrow = mnew;

    float rs = 0.f;
    #pragma unroll
    for (int nt = 0; nt < 4; ++nt) {
      float p0 = __expf(st[nt][0] - mnew);
      float p1 = __expf(st[nt][1] - mnew);
      float p2 = __expf(st[nt][2] - mnew);
      float p3 = __expf(st[nt][3] - mnew);
      rs += (p0 + p1) + (p2 + p3);
      uint2 w;
      w.x = packtrunc(p0, p1);
      w.y = packtrunc(p2, p3);
      *(uint2*)&PsW[l16 * 72 + nt * 16 + quad * 4] = w;
    }
    rs += __shfl_xor(rs, 16);
    rs += __shfl_xor(rs, 32);
    lrow = lrow * alpha + rs;

    float a0 = __shfl(alpha, quad * 4 + 0);
    float a1 = __shfl(alpha, quad * 4 + 1);
    float a2 = __shfl(alpha, quad * 4 + 2);
    float a3 = __shfl(alpha, quad * 4 + 3);
    #pragma unroll
    for (int dt = 0; dt < 4; ++dt) {
      oacc[dt][0] *= a0; oacc[dt][1] *= a1; oacc[dt][2] *= a2; oacc[dt][3] *= a3;
    }

    // PV: A = P rows (per-wave LDS), B = V^T rows
    bf16x8 pa0 = *reinterpret_cast<const bf16x8*>(&PsW[l16 * 72 + quad * 8]);
    bf16x8 pa1 = *reinterpret_cast<const bf16x8*>(&PsW[l16 * 72 + 32 + quad * 8]);
    #pragma unroll
    for (int dt = 0; dt < 4; ++dt) {
      bf16x8 vb0 = *reinterpret_cast<const bf16x8*>(&Vs[(dt * 16 + l16) * 64 + kc0]);
      bf16x8 vb1 = *reinterpret_cast<const bf16x8*>(&Vs[(dt * 16 + l16) * 64 + kc1]);
      oacc[dt] = __builtin_amdgcn_mfma_f32_16x16x32_bf16(pa0, vb0, oacc[dt], 0, 0, 0);
      oacc[dt] = __builtin_amdgcn_mfma_f32_16x16x32_bf16(pa1, vb1, oacc[dt], 0, 0, 0);
    }
  }

  // epilogue: normalize, stage all 128 rows in Ps, coalesced writes
  float invl = lrow > 0.f ? 1.f / lrow : 0.f;
  float i0 = __shfl(invl, quad * 4 + 0);
  float i1 = __shfl(invl, quad * 4 + 1);
  float i2 = __shfl(invl, quad * 4 + 2);
  float i3 = __shfl(invl, quad * 4 + 3);
  __syncthreads();
  #pragma unroll
  for (int dt = 0; dt < 4; ++dt) {
    int lr = wave * 16 + quad * 4;
    Ps[(lr + 0) * 72 + dt * 16 + l16] = f2b(oacc[dt][0] * i0);
    Ps[(lr + 1) * 72 + dt * 16 + l16] = f2b(oacc[dt][1] * i1);
    Ps[(lr + 2) * 72 + dt * 16 + l16] = f2b(oacc[dt][2] * i2);
    Ps[(lr + 3) * 72 + dt * 16 + l16] = f2b(oacc[dt][3] * i3);
  }
  __syncthreads();
  {
    int lr = tid >> 2, cb = (tid & 3) * 16;
    int n = qt * 128 + lr;
    unsigned short* dst = o + ((size_t)(b * 2048 + n)) * 1024 + h * 64 + cb;
    const unsigned short* src = Ps + lr * 72 + cb;
    ((uint4*)dst)[0] = *(const uint4*)(src);
    ((uint4*)dst)[1] = *(const uint4*)(src + 8);
  }
}

// ---------------- launch ----------------

extern "C" void kernel_launch(void* const* d_in, const int* in_sizes, int n_in,
                              void* d_out, int out_size, void* d_ws, size_t ws_size,
                              hipStream_t stream) {
  const float* x       = (const float*)d_in[0];
  const float* c       = (const float*)d_in[1];
  const int*   amask   = (const int*)d_in[2];
  const float* norm_w  = (const float*)d_in[3];
  const float* scale_w = (const float*)d_in[4];
  const float* scale_b = (const float*)d_in[5];
  const float* shift_w = (const float*)d_in[6];
  const float* shift_b = (const float*)d_in[7];
  const float* qkv_w   = (const float*)d_in[8];
  const float* proj_w  = (const float*)d_in[9];
  const float* proj_b  = (const float*)d_in[10];
  const float* mlp_w1  = (const float*)d_in[11];
  const float* mlp_b1  = (const float*)d_in[12];
  const float* mlp_w2  = (const float*)d_in[13];
  const float* mlp_b2  = (const float*)d_in[14];

  char* ws = (char*)d_ws;
  unsigned short* wqkv  = (unsigned short*)(ws + 0);
  unsigned short* wproj = (unsigned short*)(ws + 6291456);
  unsigned short* wmlp1 = (unsigned short*)(ws + 8388608);   // interleaved gate/up rows
  unsigned short* wmlp2 = (unsigned short*)(ws + 25165824);
  float* scale_o        = (float*)(ws + 33554432);
  float* shift_o        = (float*)(ws + 33562624);
  unsigned short* hbuf  = (unsigned short*)(ws + 33570816);
  unsigned short* qbuf  = (unsigned short*)(ws + 41959424);
  unsigned short* kbuf  = (unsigned short*)(ws + 50348032);
  unsigned short* vbuf  = (unsigned short*)(ws + 58736640);
  unsigned short* abuf  = (unsigned short*)(ws + 67125248);
  unsigned short* gbuf  = qbuf;
  float* x1             = (float*)(ws + 75513856);

  cvt4_kernel<<<16384, 256, 0, stream>>>(qkv_w, proj_w, mlp_w1, mlp_w2,
                                         wqkv, wproj, wmlp1, wmlp2);

  cond_kernel<<<32, 256, 0, stream>>>(c, scale_w, scale_b, shift_w, shift_b, scale_o, shift_o);

  adaln_kernel<<<4096, 256, 0, stream>>>(x, norm_w, scale_o, shift_o, hbuf);

  gemm_k<1, 128><<<dim3(24, 32), 256, 0, stream>>>(hbuf, wqkv, nullptr, nullptr,
                                                   qbuf, kbuf, vbuf, 4096, 3072, 1024);

  attn_kernel<<<dim3(32, 16), 512, 0, stream>>>(qbuf, kbuf, vbuf, amask, abuf);

  gemm_k<0, 64><<<dim3(8, 64), 256, 0, stream>>>(abuf, wproj, proj_b, x,
                                                 x1, nullptr, nullptr, 4096, 1024, 1024);

  adaln_kernel<<<4096, 256, 0, stream>>>(x1, norm_w, scale_o, shift_o, hbuf);

  gemm_k<2, 128><<<dim3(64, 32), 256, 0, stream>>>(hbuf, wmlp1, mlp_b1, nullptr,
                                                   gbuf, nullptr, nullptr, 4096, 8192, 1024);

  gemm_k<0, 64><<<dim3(8, 64), 256, 0, stream>>>(gbuf, wmlp2, mlp_b2, x1,
                                                 d_out, nullptr, nullptr, 4096, 1024, 4096);

  (void)in_sizes; (void)n_in; (void)out_size; (void)ws_size;
}